// Round 1
// baseline (86.680 us; speedup 1.0000x reference)
//
#include <hip/hip_runtime.h>
#include <stdint.h>
#include <math.h>

#define B_    4
#define H_    192
#define W_    192
#define HW    (H_*W_)            // 36864
#define NPIX  (B_*HW)            // 147456
#define C_V   10
#define C_F   64
#define C_D   16
#define C_ALL (C_V+C_F+C_D)      // 90
#define NBINS 65536
#define CAP   3072               // bin-b* list capacity per batch (expected ~150)

// ---- workspace layout (bytes) ----
#define OFF_HIST   0u
#define OFF_COUNT  (4u*NBINS*4u)            // 1,048,576
#define OFF_SELX   (OFF_COUNT + 64u)
#define ZERO_BYTES (OFF_SELX + (uint32_t)NPIX)
#define OFF_KEY    ZERO_BYTES
#define OFF_G      (OFF_KEY + (uint32_t)NPIX*4u)
#define OFF_RES    (OFF_G + (uint32_t)NPIX) // res: bstar[4], usage_before[4], hi_limit[4]
#define OFF_LIST   (OFF_RES + 64u)

__device__ __forceinline__ uint32_t costOf(uint32_t g) {
    return g == 0u ? 10u : (g == 1u ? 5u : 2u);
}

// budget_per_sample = float32(budget / B); integer greedy compare
// usage+c <= bps  <=>  usage+c <= floor(bps)   (usage,c exact ints)
__device__ __forceinline__ uint32_t budgetInt(const int* bptr) {
    double bps = (double)bptr[0] / (double)B_;
    float f = (float)bps;
    return (uint32_t)floorf(f);
}

// K1: per-pixel best utility / group / sortable key, + cost histogram by top-16 key bits
__global__ void k_prep(const float* __restrict__ util, uint32_t* __restrict__ key,
                       uint8_t* __restrict__ gArr, uint32_t* __restrict__ hist) {
    int i = blockIdx.x * blockDim.x + threadIdx.x;
    if (i >= NPIX) return;
    const float* u = util + (size_t)i * 3;
    float u0 = u[0], u1 = u[1], u2 = u[2];
    float best = u0; uint32_t g = 0;
    if (u1 > best) { best = u1; g = 1; }   // strict > keeps first max (jnp.argmax)
    if (u2 > best) { best = u2; g = 2; }
    uint32_t k = 0u;
    if (best > 0.0f) k = __float_as_uint(best) | 0x80000000u;  // ascending-order key; 0 = invalid
    key[i] = k;
    gArr[i] = (uint8_t)g;
    if (k) {
        int b = i / HW;
        atomicAdd(&hist[(size_t)b * NBINS + (k >> 16)], costOf(g));
    }
}

// K2: per batch, descending cumulative over 65536 bins -> crossing bin b*, usage_before
__global__ __launch_bounds__(1024) void k_cutoff(const uint32_t* __restrict__ hist,
                                                 const int* __restrict__ budget_ptr,
                                                 uint32_t* __restrict__ res) {
    int b = blockIdx.x;
    uint32_t budget = budgetInt(budget_ptr);
    __shared__ uint32_t scan[1024];
    __shared__ uint32_t f_bstar, f_usage;
    if (threadIdx.x == 0) { f_bstar = 0xFFFFFFFFu; f_usage = 0u; }
    int t = threadIdx.x;
    const uint32_t* hb = hist + (size_t)b * NBINS;
    int hi = 65535 - 64 * t;                 // chunk t covers bins hi .. hi-63 (descending)
    uint32_t cs = 0;
    for (int j = 0; j < 64; ++j) cs += hb[hi - j];
    scan[t] = cs;
    __syncthreads();
    for (int off = 1; off < 1024; off <<= 1) {   // Hillis-Steele inclusive scan
        uint32_t v = (t >= off) ? scan[t - off] : 0u;
        __syncthreads();
        scan[t] += v;
        __syncthreads();
    }
    uint32_t incl = scan[t], excl = incl - cs;
    if (excl <= budget && incl > budget) {       // first crossing lives in this chunk
        uint32_t cum = excl;
        for (int j = 0; j < 64; ++j) {
            uint32_t hv = hb[hi - j];
            if (cum + hv > budget) { f_bstar = (uint32_t)(hi - j); f_usage = cum; break; }
            cum += hv;
        }
    }
    __syncthreads();
    if (threadIdx.x == 0) {
        uint32_t bs = f_bstar;
        res[b]     = bs;                         // bstar (0xFFFFFFFF = no crossing)
        res[4 + b] = f_usage;                    // usage before bin b*
        uint32_t hl;
        if (bs == 0xFFFFFFFFu)      hl = 1u;            // no crossing: all valid selected
        else if (bs >= 0xFFFFu)     hl = 0xFFFFFFFFu;   // paranoia guard
        else                        hl = (bs + 1u) << 16;
        res[8 + b] = hl;                         // keys >= hl are auto-selected
    }
}

// K3: collect bin-b* items per batch
__global__ void k_collect(const uint32_t* __restrict__ key, const uint8_t* __restrict__ gArr,
                          const uint32_t* __restrict__ res, uint32_t* __restrict__ count,
                          uint64_t* __restrict__ list) {
    int i = blockIdx.x * blockDim.x + threadIdx.x;
    if (i >= NPIX) return;
    uint32_t k = key[i];
    if (!k) return;
    int b = i / HW;
    if ((k >> 16) != res[b]) return;
    uint32_t idx = atomicAdd(&count[b], 1u);
    if (idx < CAP) {
        uint32_t pix = (uint32_t)(i - b * HW);   // < 36864, fits 16 bits
        // ascending sort key: (~k, pix)  ->  utility desc, flat idx asc (stable-sort ties)
        uint64_t e = ((uint64_t)(~k) << 32) | ((uint64_t)pix << 2) | (uint64_t)gArr[i];
        list[(size_t)b * CAP + idx] = e;
    }
}

// K4: exact greedy in bin b* (LDS rank-sort + serial replay), then <=4 tail picks below b*
__global__ __launch_bounds__(512) void k_scan(const uint32_t* __restrict__ key,
                                              const uint8_t* __restrict__ gArr,
                                              const uint32_t* __restrict__ res,
                                              const uint32_t* __restrict__ count,
                                              const uint64_t* __restrict__ list,
                                              const int* __restrict__ budget_ptr,
                                              uint8_t* __restrict__ selx) {
    int b = blockIdx.x;
    uint32_t bstar = res[b];
    if (bstar == 0xFFFFFFFFu) return;            // budget never crossed
    uint32_t budget = budgetInt(budget_ptr);

    __shared__ uint64_t e[CAP];
    __shared__ uint64_t s[CAP];
    __shared__ uint64_t red[512];
    __shared__ uint32_t sh_r, sh_poskey, sh_pospix;

    uint32_t cnt = count[b];
    int n = (int)(cnt < (uint32_t)CAP ? cnt : (uint32_t)CAP);
    const uint64_t* lb = list + (size_t)b * CAP;
    for (int i = threadIdx.x; i < n; i += blockDim.x) e[i] = lb[i];
    __syncthreads();
    // rank sort (all composite keys distinct: pix unique per batch)
    for (int i = threadIdx.x; i < n; i += blockDim.x) {
        uint64_t ei = e[i];
        int rk = 0;
        for (int j = 0; j < n; ++j) rk += (e[j] < ei);
        s[rk] = ei;
    }
    __syncthreads();
    if (threadIdx.x == 0) {
        uint32_t usage = res[4 + b];
        uint8_t* sx = selx + (size_t)b * HW;
        for (int i = 0; i < n; ++i) {
            uint64_t ei = s[i];
            uint32_t g = (uint32_t)(ei & 3u);
            uint32_t c = costOf(g);
            if (usage + c <= budget) { usage += c; sx[(ei >> 2) & 0xFFFFu] = 1; }
        }
        sh_r = budget - usage;                   // always <= 9 here
        sh_poskey = bstar << 16;                 // resume position: just after bin b*
        sh_pospix = 0xFFFFFFFFu;
    }
    __syncthreads();

    // tail: pick next item in sort order with cost <= r; at most 4 picks possible
    const uint32_t* kb = key + (size_t)b * HW;
    const uint8_t*  gb = gArr + (size_t)b * HW;
    for (int round = 0; round < 8; ++round) {
        uint32_t r = sh_r;
        if (r < 2u) break;
        uint32_t pkey = sh_poskey, ppix = sh_pospix;
        uint64_t best = 0;
        for (int i = threadIdx.x; i < HW; i += blockDim.x) {
            uint32_t k = kb[i];
            if (!k) continue;
            if (!(k < pkey || (k == pkey && (uint32_t)i > ppix))) continue;
            if (costOf(gb[i]) > r) continue;
            uint64_t m = ((uint64_t)k << 16) | (uint64_t)(65535u - (uint32_t)i);
            if (m > best) best = m;              // max key, then min pix
        }
        red[threadIdx.x] = best;
        __syncthreads();
        for (int off = 256; off > 0; off >>= 1) {
            if ((int)threadIdx.x < off) {
                uint64_t o = red[threadIdx.x + off];
                if (o > red[threadIdx.x]) red[threadIdx.x] = o;
            }
            __syncthreads();
        }
        if (threadIdx.x == 0) {
            uint64_t m = red[0];
            if (m == 0) sh_r = 0;                // nothing fits -> done
            else {
                uint32_t pix = 65535u - (uint32_t)(m & 0xFFFFu);
                uint32_t k   = (uint32_t)(m >> 16);
                uint32_t c   = costOf(gb[pix]);
                selx[(size_t)b * HW + pix] = 1;
                sh_r -= c;
                sh_poskey = k; sh_pospix = pix;
            }
        }
        __syncthreads();
    }
}

// K5: sel_idx output
__global__ void k_selidx(const uint32_t* __restrict__ key, const uint8_t* __restrict__ gArr,
                         const uint8_t* __restrict__ selx, const uint32_t* __restrict__ res,
                         float* __restrict__ selOut) {
    int i = blockIdx.x * blockDim.x + threadIdx.x;
    if (i >= NPIX) return;
    int b = i / HW;
    uint32_t k = key[i];
    bool sel = (k != 0u && k >= res[8 + b]) || (selx[i] != 0);
    selOut[i] = sel ? (float)gArr[i] : -1.0f;
}

// K6: masked sparse BEV, float4-vectorized
__global__ void k_sparse(const float* __restrict__ collab, const float* __restrict__ selOut,
                         float* __restrict__ out) {
    int tid = blockIdx.x * blockDim.x + threadIdx.x;   // [0, HW/4)
    int c = blockIdx.y, b = blockIdx.z;
    if (tid >= HW / 4) return;
    float want = (c < C_V) ? 0.0f : ((c < C_V + C_F) ? 1.0f : 2.0f);
    size_t po = (size_t)b * HW + (size_t)tid * 4;
    float4 s4 = *(const float4*)(selOut + po);
    size_t co = ((size_t)(b * C_ALL + c)) * HW + (size_t)tid * 4;
    float4 v = *(const float4*)(collab + co);
    float4 o;
    o.x = (s4.x == want) ? v.x : 0.0f;
    o.y = (s4.y == want) ? v.y : 0.0f;
    o.z = (s4.z == want) ? v.z : 0.0f;
    o.w = (s4.w == want) ? v.w : 0.0f;
    *(float4*)(out + co) = o;
}

extern "C" void kernel_launch(void* const* d_in, const int* in_sizes, int n_in,
                              void* d_out, int out_size, void* d_ws, size_t ws_size,
                              hipStream_t stream) {
    (void)in_sizes; (void)n_in; (void)out_size; (void)ws_size;
    const float* collab = (const float*)d_in[0];
    const float* util   = (const float*)d_in[1];
    const int*   budget = (const int*)d_in[2];

    uint8_t*  ws    = (uint8_t*)d_ws;
    uint32_t* hist  = (uint32_t*)(ws + OFF_HIST);
    uint32_t* count = (uint32_t*)(ws + OFF_COUNT);
    uint8_t*  selx  = ws + OFF_SELX;
    uint32_t* key   = (uint32_t*)(ws + OFF_KEY);
    uint8_t*  g     = ws + OFF_G;
    uint32_t* res   = (uint32_t*)(ws + OFF_RES);
    uint64_t* list  = (uint64_t*)(ws + OFF_LIST);

    float* outSparse = (float*)d_out;
    float* outSel    = outSparse + (size_t)B_ * C_ALL * HW;

    hipMemsetAsync(d_ws, 0, ZERO_BYTES, stream);

    k_prep   <<<(NPIX + 255) / 256, 256, 0, stream>>>(util, key, g, hist);
    k_cutoff <<<B_, 1024, 0, stream>>>(hist, budget, res);
    k_collect<<<(NPIX + 255) / 256, 256, 0, stream>>>(key, g, res, count, list);
    k_scan   <<<B_, 512, 0, stream>>>(key, g, res, count, list, budget, selx);
    k_selidx <<<(NPIX + 255) / 256, 256, 0, stream>>>(key, g, selx, res, outSel);
    dim3 grid6(HW / 4 / 256, C_ALL, B_);
    k_sparse <<<grid6, 256, 0, stream>>>(collab, outSel, outSparse);
}